// Round 7
// baseline (824.798 us; speedup 1.0000x reference)
//
#include <hip/hip_runtime.h>

#define N_NODES 100000
#define N_EDGES 1600000
#define DIM 256
#define NBINS 196      // ceil(100000 / 512)
#define BINCAP 16384   // per-bin record capacity (expected 8163, sigma ~90)

typedef unsigned short bf16u;
typedef __attribute__((ext_vector_type(8))) short bf16x8s;
typedef __attribute__((ext_vector_type(4))) float f32x4;

__device__ __forceinline__ float bf2f(unsigned int u16) {
    union { unsigned int i; float f; } x; x.i = u16 << 16; return x.f;
}
__device__ __forceinline__ float hi2f(unsigned int u) {
    union { unsigned int i; float f; } x; x.i = u & 0xffff0000u; return x.f;
}
__device__ __forceinline__ float lo2f(unsigned int u) {
    union { unsigned int i; float f; } x; x.i = u << 16; return x.f;
}
__device__ __forceinline__ bf16u f2bf(float f) {
    union { float f; unsigned int i; } x; x.f = f;
    unsigned int i = x.i;
    return (bf16u)((i + 0x7fffu + ((i >> 16) & 1u)) >> 16);
}
__device__ __forceinline__ float loadv(const void* p, size_t i, int isf32) {
    return isf32 ? ((const float*)p)[i] : bf2f(((const bf16u*)p)[i]);
}
__device__ __forceinline__ void async_copy16(const void* g, void* l) {
    __builtin_amdgcn_global_load_lds((const __attribute__((address_space(1))) void*)g,
                                     (__attribute__((address_space(3))) void*)l, 16, 0, 0);
}

// ---------------- runtime format probes (+ zero bin fills + zero sums) ----------------
__global__ void detect_flags(const unsigned* xw, const int* ei, int* flags, int* gBinFill,
                             float* sums) {
    __shared__ int cnt, nz;
    if (threadIdx.x == 0) { cnt = 0; nz = 0; }
    __syncthreads();
    gBinFill[threadIdx.x] = 0;                     // 256 >= NBINS
#pragma unroll
    for (int i = 0; i < 6; ++i) sums[i * 256 + threadIdx.x] = 0.f;  // sums0..2, 1536 floats
    unsigned u = xw[threadIdx.x];
    float av = fabsf(bf2f(u & 0xffffu));
    if (av > 1e-5f && av < 50.f) atomicAdd(&cnt, 1);
    if (ei[2 * threadIdx.x + 1] != 0) atomicAdd(&nz, 1);
    __syncthreads();
    if (threadIdx.x == 0) {
        flags[0] = (cnt >= 128) ? 0 : 1;           // 1 = inputs are float32
        if (nz == 0) { flags[1] = 2; flags[2] = 2 * N_EDGES; }
        else         { flags[1] = 1; flags[2] = N_EDGES; }
    }
}

// ---------------- weight transpose: Wt[n][k] = bf16(W[k][n]) ----------------
__global__ void transpose_w(const void* W0, const void* W1, const void* W2, const void* W3,
                            bf16u* Wt, const int* flags) {
    __shared__ bf16u tile[64][65];
    int isf32 = flags[0];
    const void* W = (blockIdx.y == 0) ? W0 : (blockIdx.y == 1) ? W1 : (blockIdx.y == 2) ? W2 : W3;
    bf16u* out = Wt + (size_t)blockIdx.y * DIM * DIM;
    int t = threadIdx.x;
    int tx = t & 63, ty = t >> 6;
    int k0 = (blockIdx.x >> 2) * 64, n0 = (blockIdx.x & 3) * 64;
#pragma unroll
    for (int i = 0; i < 16; ++i) {
        int r = ty + i * 4;
        tile[tx][r] = f2bf(loadv(W, (size_t)(k0 + r) * DIM + (n0 + tx), isf32));
    }
    __syncthreads();
#pragma unroll
    for (int i = 0; i < 16; ++i) {
        int r = ty + i * 4;
        out[(size_t)(n0 + r) * DIM + (k0 + tx)] = tile[r][tx];
    }
}

// ---------------- CSR build, pass A: bucket scatter by dst>>9 ----------------
__global__ __launch_bounds__(256) void bin_scatter(const int* __restrict__ ei,
                                                   const int* __restrict__ flags,
                                                   uint2* __restrict__ gRec,
                                                   int* __restrict__ gBinFill) {
    __shared__ int cnt[256];       // bin counts, then bin bases
    __shared__ int cur[256];
    __shared__ uint2 rec[4096];    // 32 KB
    int t = threadIdx.x;
    cnt[t] = 0; cur[t] = 0;
    __syncthreads();
    int st = flags[1], ofs = flags[2];
    int e0 = blockIdx.x * 4096;
#pragma unroll
    for (int i = 0; i < 16; ++i) {
        int e = e0 + i * 256 + t;
        uint2 r;
        if (e < N_EDGES) {
            r.x = (unsigned)ei[(size_t)ofs + (size_t)e * st];
            r.y = (unsigned)ei[(size_t)e * st];
            atomicAdd(&cnt[r.x >> 9], 1);
        } else {
            r.x = 0xffffffffu; r.y = 0;
        }
        rec[i * 256 + t] = r;
    }
    __syncthreads();
    if (t < NBINS) {
        int c = cnt[t];
        int b = (c > 0) ? atomicAdd(&gBinFill[t], c) : 0;
        cnt[t] = b;                 // repurpose as base
    }
    __syncthreads();
#pragma unroll
    for (int i = 0; i < 16; ++i) {
        uint2 r = rec[i * 256 + t];
        if (r.x != 0xffffffffu) {
            int b = r.x >> 9;
            int li = atomicAdd(&cur[b], 1);
            int pos = cnt[b] + li;
            if (pos < BINCAP) gRec[(size_t)b * BINCAP + pos] = r;
        }
    }
}

// ---------------- CSR build, pass A2: exclusive scan over bin fills ----------------
__global__ void bin_scan(const int* gBinFill, int* binBase) {
    __shared__ int s[256];
    int t = threadIdx.x;
    s[t] = (t < NBINS) ? gBinFill[t] : 0;
    __syncthreads();
    for (int off = 1; off < 256; off <<= 1) {
        int v = (t >= off) ? s[t - off] : 0;
        __syncthreads();
        s[t] += v;
        __syncthreads();
    }
    binBase[t + 1] = s[t];
    if (t == 0) binBase[0] = 0;
}

// ---------------- CSR build, pass B: per-bin counting sort -> rp, col ----------------
__global__ __launch_bounds__(256) void bin_csr(const uint2* __restrict__ gRec,
                                               const int* __restrict__ gBinFill,
                                               const int* __restrict__ binBase,
                                               int* __restrict__ rp, int* __restrict__ col) {
    __shared__ int cntA[512], scanB[512], noff[512], ncur[512];
    int bin = blockIdx.x, t = threadIdx.x;
    int cnt = gBinFill[bin];
    if (cnt > BINCAP) cnt = BINCAP;
    int gbase = binBase[bin], lo = bin << 9;
    cntA[t] = 0; cntA[t + 256] = 0; ncur[t] = 0; ncur[t + 256] = 0;
    __syncthreads();
    const uint2* R = gRec + (size_t)bin * BINCAP;
    for (int j = t; j < cnt; j += 256) atomicAdd(&cntA[(int)R[j].x - lo], 1);
    __syncthreads();
    scanB[t] = cntA[t]; scanB[t + 256] = cntA[t + 256];
    __syncthreads();
    for (int off = 1; off < 512; off <<= 1) {
        int v0 = (t >= off) ? scanB[t - off] : 0;
        int v1 = (t + 256 >= off) ? scanB[t + 256 - off] : 0;
        __syncthreads();
        scanB[t] += v0; scanB[t + 256] += v1;
        __syncthreads();
    }
    noff[t] = scanB[t] - cntA[t];
    noff[t + 256] = scanB[t + 256] - cntA[t + 256];
    __syncthreads();
    int n0 = lo + t, n1 = lo + t + 256;
    if (n0 < N_NODES) rp[n0] = gbase + noff[t];
    if (n1 < N_NODES) rp[n1] = gbase + noff[t + 256];
    if (bin == 0 && t == 0) rp[N_NODES] = N_EDGES;
    for (int j = t; j < cnt; j += 256) {
        uint2 r = R[j];
        int k = (int)r.x - lo;
        int li = atomicAdd(&ncur[k], 1);
        col[gbase + noff[k] + li] = (int)r.y;
    }
}

// ---------------- BN0 column stats (dual dtype input) ----------------
__global__ void col_stats(const void* X, int nrows, float* sums, const int* flags, int dual) {
    __shared__ float ls[512];
    int isf32 = dual ? flags[0] : 0;
    int t = threadIdx.x;
    ls[t] = 0.f; ls[t + 256] = 0.f;
    __syncthreads();
    int rpb = (nrows + gridDim.x - 1) / gridDim.x;
    int r0 = blockIdx.x * rpb;
    int r1 = r0 + rpb; if (r1 > nrows) r1 = nrows;
    int cg = (t & 31) * 8;
    float s[8], q[8];
#pragma unroll
    for (int j = 0; j < 8; ++j) { s[j] = 0.f; q[j] = 0.f; }
    if (isf32) {
        for (int r = r0 + (t >> 5); r < r1; r += 8) {
            const float* xp = (const float*)X + (size_t)r * DIM + cg;
            f32x4 a = *(const f32x4*)xp, b = *(const f32x4*)(xp + 4);
#pragma unroll
            for (int j = 0; j < 4; ++j) {
                s[j] += a[j]; q[j] += a[j] * a[j];
                s[4 + j] += b[j]; q[4 + j] += b[j] * b[j];
            }
        }
    } else {
        for (int r = r0 + (t >> 5); r < r1; r += 8) {
            size_t base = (size_t)r * DIM + cg;
#pragma unroll
            for (int j = 0; j < 8; ++j) {
                float f = bf2f(((const bf16u*)X)[base + j]);
                s[j] += f; q[j] += f * f;
            }
        }
    }
#pragma unroll
    for (int j = 0; j < 8; ++j) {
        atomicAdd(&ls[cg + j], s[j]);
        atomicAdd(&ls[256 + cg + j], q[j]);
    }
    __syncthreads();
    atomicAdd(&sums[t], ls[t]);
    atomicAdd(&sums[256 + t], ls[256 + t]);
}

__global__ void bn_finalize(const float* sums, const void* gamma, const void* beta,
                            float* sc, float* sh, float inv_n, const int* flags) {
    int isf32 = flags[0];
    int t = threadIdx.x;
    float mu = sums[t] * inv_n;
    float var = sums[256 + t] * inv_n - mu * mu;
    float rs = rsqrtf(var + 1e-5f);
    float g = loadv(gamma, t, isf32), b = loadv(beta, t, isf32);
    sc[t] = rs * g;
    sh[t] = b - mu * rs * g;
}

// ---------------- vectorized BN apply (BN0 only): y = x*sc+sh, writes bf16 ----------------
__global__ void bn_apply(const void* X, const float* sc, const float* sh, bf16u* Y,
                         const int* flags, int dual, int relu) {
    int isf32 = dual ? flags[0] : 0;
    size_t i = (size_t)blockIdx.x * 256 + threadIdx.x;
    int c = ((int)(i & 31)) * 8;
    size_t base = i * 8;
    float v[8];
    if (isf32) {
        f32x4 x0 = *(const f32x4*)((const float*)X + base);
        f32x4 x1 = *(const f32x4*)((const float*)X + base + 4);
#pragma unroll
        for (int j = 0; j < 4; ++j) { v[j] = x0[j]; v[4 + j] = x1[j]; }
    } else {
        uint4 u = *(const uint4*)((const bf16u*)X + base);
        v[0] = lo2f(u.x); v[1] = hi2f(u.x);
        v[2] = lo2f(u.y); v[3] = hi2f(u.y);
        v[4] = lo2f(u.z); v[5] = hi2f(u.z);
        v[6] = lo2f(u.w); v[7] = hi2f(u.w);
    }
    f32x4 s0 = *(const f32x4*)(sc + c), s1 = *(const f32x4*)(sc + c + 4);
    f32x4 h0 = *(const f32x4*)(sh + c), h1 = *(const f32x4*)(sh + c + 4);
    float y[8];
#pragma unroll
    for (int j = 0; j < 4; ++j) {
        y[j]     = v[j]     * s0[j] + h0[j];
        y[4 + j] = v[4 + j] * s1[j] + h1[j];
    }
    if (relu) {
#pragma unroll
        for (int j = 0; j < 8; ++j) y[j] = fmaxf(y[j], 0.f);
    }
    uint4 ov;
    ov.x = (unsigned)f2bf(y[0]) | ((unsigned)f2bf(y[1]) << 16);
    ov.y = (unsigned)f2bf(y[2]) | ((unsigned)f2bf(y[3]) << 16);
    ov.z = (unsigned)f2bf(y[4]) | ((unsigned)f2bf(y[5]) << 16);
    ov.w = (unsigned)f2bf(y[6]) | ((unsigned)f2bf(y[7]) << 16);
    *(uint4*)(Y + base) = ov;
}

// ---------------- aggregation: 16B/lane, unroll-8 ----------------
__global__ __launch_bounds__(256) void aggregate(const bf16u* __restrict__ h,
                                                 const int* __restrict__ rp,
                                                 const int* __restrict__ col,
                                                 bf16u* __restrict__ out) {
    int node = blockIdx.x * 4 + (threadIdx.x >> 6);
    int lane = threadIdx.x & 63;
    int p = lane >> 5, c = lane & 31;
    const uint4* hv = (const uint4*)h;            // 32 x 16B per row
    float acc[8];
    if (p == 0) {
        uint4 u = hv[(size_t)node * 32 + c];
        acc[0] = lo2f(u.x); acc[1] = hi2f(u.x);
        acc[2] = lo2f(u.y); acc[3] = hi2f(u.y);
        acc[4] = lo2f(u.z); acc[5] = hi2f(u.z);
        acc[6] = lo2f(u.w); acc[7] = hi2f(u.w);
    } else {
#pragma unroll
        for (int j = 0; j < 8; ++j) acc[j] = 0.f;
    }
    int e = rp[node], e1 = rp[node + 1];
    for (; e + 8 <= e1; e += 8) {
        int s0 = col[e + p], s1 = col[e + 2 + p], s2 = col[e + 4 + p], s3 = col[e + 6 + p];
        uint4 a = hv[(size_t)s0 * 32 + c];
        uint4 b = hv[(size_t)s1 * 32 + c];
        uint4 d = hv[(size_t)s2 * 32 + c];
        uint4 f = hv[(size_t)s3 * 32 + c];
        acc[0] += lo2f(a.x); acc[1] += hi2f(a.x); acc[2] += lo2f(a.y); acc[3] += hi2f(a.y);
        acc[4] += lo2f(a.z); acc[5] += hi2f(a.z); acc[6] += lo2f(a.w); acc[7] += hi2f(a.w);
        acc[0] += lo2f(b.x); acc[1] += hi2f(b.x); acc[2] += lo2f(b.y); acc[3] += hi2f(b.y);
        acc[4] += lo2f(b.z); acc[5] += hi2f(b.z); acc[6] += lo2f(b.w); acc[7] += hi2f(b.w);
        acc[0] += lo2f(d.x); acc[1] += hi2f(d.x); acc[2] += lo2f(d.y); acc[3] += hi2f(d.y);
        acc[4] += lo2f(d.z); acc[5] += hi2f(d.z); acc[6] += lo2f(d.w); acc[7] += hi2f(d.w);
        acc[0] += lo2f(f.x); acc[1] += hi2f(f.x); acc[2] += lo2f(f.y); acc[3] += hi2f(f.y);
        acc[4] += lo2f(f.z); acc[5] += hi2f(f.z); acc[6] += lo2f(f.w); acc[7] += hi2f(f.w);
    }
    for (; e + 4 <= e1; e += 4) {
        int s0 = col[e + p], s1 = col[e + 2 + p];
        uint4 a = hv[(size_t)s0 * 32 + c];
        uint4 b = hv[(size_t)s1 * 32 + c];
        acc[0] += lo2f(a.x); acc[1] += hi2f(a.x); acc[2] += lo2f(a.y); acc[3] += hi2f(a.y);
        acc[4] += lo2f(a.z); acc[5] += hi2f(a.z); acc[6] += lo2f(a.w); acc[7] += hi2f(a.w);
        acc[0] += lo2f(b.x); acc[1] += hi2f(b.x); acc[2] += lo2f(b.y); acc[3] += hi2f(b.y);
        acc[4] += lo2f(b.z); acc[5] += hi2f(b.z); acc[6] += lo2f(b.w); acc[7] += hi2f(b.w);
    }
    for (; e < e1; e += 2) {
        int idx = e + p;
        if (idx < e1) {
            uint4 a = hv[(size_t)col[idx] * 32 + c];
            acc[0] += lo2f(a.x); acc[1] += hi2f(a.x); acc[2] += lo2f(a.y); acc[3] += hi2f(a.y);
            acc[4] += lo2f(a.z); acc[5] += hi2f(a.z); acc[6] += lo2f(a.w); acc[7] += hi2f(a.w);
        }
    }
#pragma unroll
    for (int j = 0; j < 8; ++j) acc[j] += __shfl_xor(acc[j], 32);
    if (p == 0) {
        uint4 ov;
        ov.x = (unsigned)f2bf(acc[0]) | ((unsigned)f2bf(acc[1]) << 16);
        ov.y = (unsigned)f2bf(acc[2]) | ((unsigned)f2bf(acc[3]) << 16);
        ov.z = (unsigned)f2bf(acc[4]) | ((unsigned)f2bf(acc[5]) << 16);
        ov.w = (unsigned)f2bf(acc[6]) | ((unsigned)f2bf(acc[7]) << 16);
        ((uint4*)out)[(size_t)node * 32 + c] = ov;
    }
}

// ---------------- MFMA GEMM: double-buffered LDS, 1 barrier/K-iter, XCD-paired ----------------
// stage(k+1) issued right after the barrier; tile-k compute overlaps the copies' flight.
// Fused input-BN+ReLU variant (bnsc/bnsh): T14 split — global loads early, convert+ds_write late.
__global__ __launch_bounds__(256) void gemm_bias(const bf16u* __restrict__ A,
                                                 const bf16u* __restrict__ Wt,
                                                 const void* __restrict__ bias,
                                                 void* __restrict__ Cout, int mrows,
                                                 const int* __restrict__ flags,
                                                 int relu, int f32out,
                                                 float* __restrict__ stats,
                                                 const float* __restrict__ bnsc,
                                                 const float* __restrict__ bnsh) {
    __shared__ bf16u As[2][128 * 64];   // 2 x 16 KB, XOR-swizzled k-chunks
    __shared__ bf16u Bs[2][128 * 64];
    __shared__ float lsum[256];
    int isf32 = flags[0];
    int t = threadIdx.x;
    int w = t >> 6, lane = t & 63;
    int lr = lane & 15, lq = lane >> 4;
    int wm = w >> 1, wn = w & 1;
    // bijective XCD chunk remap: nwg=1564, q=195, r=4 (m204)
    int xcd = blockIdx.x & 7, j0 = blockIdx.x >> 3;
    int wkid = ((xcd < 4) ? xcd * 196 : 784 + (xcd - 4) * 195) + j0;
    int rowBase = (wkid >> 1) * 128, colBase = (wkid & 1) * 128;
    f32x4 acc[4][4] = {};
    lsum[t] = 0.f;
    int srow = t >> 3;                           // 0..31
    int g8   = ((t & 7) ^ ((t >> 3) & 7)) * 8;   // swizzled k element offset
    int ldsOff = (t >> 3) * 64 + (t & 7) * 8;    // == (p=0 row)*64 + chunk; +p*2048 per p

    // ---- prologue: stage tile 0 ----
    if (bnsc) {
        f32x4 s0v = *(const f32x4*)(bnsc + g8);
        f32x4 s1v = *(const f32x4*)(bnsc + g8 + 4);
        f32x4 h0v = *(const f32x4*)(bnsh + g8);
        f32x4 h1v = *(const f32x4*)(bnsh + g8 + 4);
#pragma unroll
        for (int p = 0; p < 4; ++p) {
            int r = p * 32 + srow;
            int gr = rowBase + r; gr = (gr < mrows) ? gr : (mrows - 1);
            uint4 av = *(const uint4*)(A + (size_t)gr * 256 + g8);
            uint4 ov;
            ov.x = (unsigned)f2bf(fmaxf(lo2f(av.x) * s0v[0] + h0v[0], 0.f)) |
                   ((unsigned)f2bf(fmaxf(hi2f(av.x) * s0v[1] + h0v[1], 0.f)) << 16);
            ov.y = (unsigned)f2bf(fmaxf(lo2f(av.y) * s0v[2] + h0v[2], 0.f)) |
                   ((unsigned)f2bf(fmaxf(hi2f(av.y) * s0v[3] + h0v[3], 0.f)) << 16);
            ov.z = (unsigned)f2bf(fmaxf(lo2f(av.z) * s1v[0] + h1v[0], 0.f)) |
                   ((unsigned)f2bf(fmaxf(hi2f(av.z) * s1v[1] + h1v[1], 0.f)) << 16);
            ov.w = (unsigned)f2bf(fmaxf(lo2f(av.w) * s1v[2] + h1v[2], 0.f)) |
                   ((unsigned)f2bf(fmaxf(hi2f(av.w) * s1v[3] + h1v[3], 0.f)) << 16);
            *(uint4*)&As[0][p * 2048 + ldsOff] = ov;
            async_copy16(Wt + (size_t)(colBase + r) * 256 + g8, &Bs[0][(p * 32 + (w << 3)) * 64]);
        }
    } else {
#pragma unroll
        for (int p = 0; p < 4; ++p) {
            int r = p * 32 + srow;
            int gr = rowBase + r; gr = (gr < mrows) ? gr : (mrows - 1);
            async_copy16(A + (size_t)gr * 256 + g8, &As[0][(p * 32 + (w << 3)) * 64]);
            async_copy16(Wt + (size_t)(colBase + r) * 256 + g8, &Bs[0][(p * 32 + (w << 3)) * 64]);
        }
    }

    // ---- main loop: one barrier per K-iter ----
    for (int kt = 0; kt < 4; ++kt) {
        int b = kt & 1, bn = b ^ 1;
        int kn = (kt + 1) * 64;
        __syncthreads();                     // tile kt landed; prior reads drained
        uint4 av[4];
        if (kt < 3) {
            if (bnsc) {
                // T14: issue A global loads now; convert+write after MFMAs
#pragma unroll
                for (int p = 0; p < 4; ++p) {
                    int r = p * 32 + srow;
                    int gr = rowBase + r; gr = (gr < mrows) ? gr : (mrows - 1);
                    av[p] = *(const uint4*)(A + (size_t)gr * 256 + kn + g8);
                }
#pragma unroll
                for (int p = 0; p < 4; ++p) {
                    int r = p * 32 + srow;
                    async_copy16(Wt + (size_t)(colBase + r) * 256 + kn + g8,
                                 &Bs[bn][(p * 32 + (w << 3)) * 64]);
                }
            } else {
#pragma unroll
                for (int p = 0; p < 4; ++p) {
                    int r = p * 32 + srow;
                    int gr = rowBase + r; gr = (gr < mrows) ? gr : (mrows - 1);
                    async_copy16(A + (size_t)gr * 256 + kn + g8,
                                 &As[bn][(p * 32 + (w << 3)) * 64]);
                    async_copy16(Wt + (size_t)(colBase + r) * 256 + kn + g8,
                                 &Bs[bn][(p * 32 + (w << 3)) * 64]);
                }
            }
        }
        // compute tile kt from buffer b
#pragma unroll
        for (int ks = 0; ks < 2; ++ks) {
            bf16x8s af[4], bfv[4];
#pragma unroll
            for (int mt = 0; mt < 4; ++mt) {
                int ar = wm * 64 + mt * 16 + lr;
                af[mt] = *(const bf16x8s*)&As[b][ar * 64 + (((ks * 4 + lq) ^ (lr & 7)) * 8)];
            }
#pragma unroll
            for (int nt = 0; nt < 4; ++nt) {
                int br = wn * 64 + nt * 16 + lr;
                bfv[nt] = *(const bf16x8s*)&Bs[b][br * 64 + (((ks * 4 + lq) ^ (lr & 7)) * 8)];
            }
#pragma unroll
            for (int mt = 0; mt < 4; ++mt)
#pragma unroll
                for (int nt = 0; nt < 4; ++nt)
                    acc[mt][nt] = __builtin_amdgcn_mfma_f32_16x16x32_bf16(af[mt], bfv[nt], acc[mt][nt], 0, 0, 0);
        }
        if (bnsc && kt < 3) {
            // convert + ds_write into As[bn] (loads had the MFMA phase to land)
            f32x4 s0v = *(const f32x4*)(bnsc + kn + g8);
            f32x4 s1v = *(const f32x4*)(bnsc + kn + g8 + 4);
            f32x4 h0v = *(const f32x4*)(bnsh + kn + g8);
            f32x4 h1v = *(const f32x4*)(bnsh + kn + g8 + 4);
#pragma unroll
            for (int p = 0; p < 4; ++p) {
                uint4 ov;
                ov.x = (unsigned)f2bf(fmaxf(lo2f(av[p].x) * s0v[0] + h0v[0], 0.f)) |
                       ((unsigned)f2bf(fmaxf(hi2f(av[p].x) * s0v[1] + h0v[1], 0.f)) << 16);
                ov.y = (unsigned)f2bf(fmaxf(lo2f(av[p].y) * s0v[2] + h0v[2], 0.f)) |
                       ((unsigned)f2bf(fmaxf(hi2f(av[p].y) * s0v[3] + h0v[3], 0.f)) << 16);
                ov.z = (unsigned)f2bf(fmaxf(lo2f(av[p].z) * s1v[0] + h1v[0], 0.f)) |
                       ((unsigned)f2bf(fmaxf(hi2f(av[p].z) * s1v[1] + h1v[1], 0.f)) << 16);
                ov.w = (unsigned)f2bf(fmaxf(lo2f(av[p].w) * s1v[2] + h1v[2], 0.f)) |
                       ((unsigned)f2bf(fmaxf(hi2f(av[p].w) * s1v[3] + h1v[3], 0.f)) << 16);
                *(uint4*)&As[bn][p * 2048 + ldsOff] = ov;
            }
        }
    }

    int storef32 = f32out && isf32;
#pragma unroll
    for (int nt = 0; nt < 4; ++nt) {
        int cl = wn * 64 + nt * 16 + lr;
        int c = colBase + cl;
        float bv = loadv(bias, c, isf32);
        float ssum = 0.f, ssq = 0.f;
#pragma unroll
        for (int mt = 0; mt < 4; ++mt) {
            int r0 = rowBase + wm * 64 + mt * 16 + lq * 4;
#pragma unroll
            for (int j = 0; j < 4; ++j) {
                int r = r0 + j;
                if (r < mrows) {
                    float y = acc[mt][nt][j] + bv;
                    if (relu) y = fmaxf(y, 0.f);
                    if (storef32) ((float*)Cout)[(size_t)r * 256 + c] = y;
                    else          ((bf16u*)Cout)[(size_t)r * 256 + c] = f2bf(y);
                    ssum += y; ssq += y * y;
                }
            }
        }
        if (stats) {
            atomicAdd(&lsum[cl], ssum);
            atomicAdd(&lsum[128 + cl], ssq);
        }
    }
    if (stats) {
        __syncthreads();
        if (t < 128) {
            atomicAdd(&stats[colBase + t], lsum[t]);
            atomicAdd(&stats[256 + colBase + t], lsum[128 + t]);
        }
    }
}

extern "C" void kernel_launch(void* const* d_in, const int* in_sizes, int n_in,
                              void* d_out, int out_size, void* d_ws, size_t ws_size,
                              hipStream_t stream) {
    const void* x   = d_in[0];
    const int*  ei  = (const int*)d_in[1];
    const void* g0  = d_in[2];
    const void* b0  = d_in[3];
    const void* W1a = d_in[4];
    const void* b1a = d_in[5];
    const void* g1  = d_in[6];
    const void* bt1 = d_in[7];
    const void* W1b = d_in[8];
    const void* b1b = d_in[9];
    const void* W2a = d_in[10];
    const void* b2a = d_in[11];
    const void* g2  = d_in[12];
    const void* bt2 = d_in[13];
    const void* W2b = d_in[14];
    const void* b2b = d_in[15];

    char* ws = (char*)d_ws;
    size_t off = 0;
    auto alloc = [&](size_t bytes) {
        char* p = ws + off;
        off += (bytes + 255) & ~(size_t)255;
        return p;
    };
    const size_t FB = (size_t)N_NODES * DIM * 2;
    bf16u* bufA  = (bf16u*)alloc(FB);
    bf16u* bufB  = (bf16u*)alloc(FB);
    bf16u* Wt    = (bf16u*)alloc((size_t)4 * DIM * DIM * 2);
    int*   colA  = (int*)alloc((size_t)N_EDGES * 4);
    int*   rp    = (int*)alloc((size_t)(N_NODES + 1) * 4);
    int*   gBinFill = (int*)alloc(256 * 4);
    int*   binBase  = (int*)alloc(260 * 4);
    float* sums0 = (float*)alloc(512 * 4);
    float* sums1 = (float*)alloc(512 * 4);
    float* sums2 = (float*)alloc(512 * 4);
    float* sc    = (float*)alloc(256 * 4);
    float* sh    = (float*)alloc(256 * 4);
    int*   flags = (int*)alloc(4 * 4);

    // bucket records reuse bufB (25.7 MB < 51.2 MB); bufB only becomes live at bn_apply
    uint2* gRec = (uint2*)bufB;

    bf16u* Wt1a = Wt;
    bf16u* Wt1b = Wt + 65536;
    bf16u* Wt2a = Wt + 2 * 65536;
    bf16u* Wt2b = Wt + 3 * 65536;

    const float inv_n = 1.0f / (float)N_NODES;

    detect_flags<<<1, 256, 0, stream>>>((const unsigned*)x, ei, flags, gBinFill, sums0);
    transpose_w<<<dim3(16, 4), 256, 0, stream>>>(W1a, W1b, W2a, W2b, Wt, flags);

    // CSR via 2-level bucket sort (writes coalesced; uses bufB as scratch)
    bin_scatter<<<391, 256, 0, stream>>>(ei, flags, gRec, gBinFill);
    bin_scan<<<1, 256, 0, stream>>>(gBinFill, binBase);
    bin_csr<<<NBINS, 256, 0, stream>>>(gRec, gBinFill, binBase, rp, colA);

    // BN0: x (f32) -> bufB (bf16)
    col_stats<<<500, 256, 0, stream>>>(x, N_NODES, sums0, flags, 1);
    bn_finalize<<<1, 256, 0, stream>>>(sums0, g0, b0, sc, sh, inv_n, flags);
    bn_apply<<<12500, 256, 0, stream>>>(x, sc, sh, bufB, flags, 1, 0);

    // layer 1
    aggregate<<<25000, 256, 0, stream>>>(bufB, rp, colA, bufA);
    gemm_bias<<<1564, 256, 0, stream>>>(bufA, Wt1a, b1a, bufB, N_NODES, flags, 0, 0, sums1,
                                        nullptr, nullptr);
    bn_finalize<<<1, 256, 0, stream>>>(sums1, g1, bt1, sc, sh, inv_n, flags);
    gemm_bias<<<1564, 256, 0, stream>>>(bufB, Wt1b, b1b, bufA, N_NODES, flags, 1, 0, nullptr,
                                        sc, sh);   // fused BN+ReLU on input

    // layer 2
    aggregate<<<25000, 256, 0, stream>>>(bufA, rp, colA, bufB);
    gemm_bias<<<1564, 256, 0, stream>>>(bufB, Wt2a, b2a, bufA, N_NODES, flags, 0, 0, sums2,
                                        nullptr, nullptr);
    bn_finalize<<<1, 256, 0, stream>>>(sums2, g2, bt2, sc, sh, inv_n, flags);
    gemm_bias<<<1564, 256, 0, stream>>>(bufA, Wt2b, b2b, d_out, N_NODES, flags, 1, 1, nullptr,
                                        sc, sh);   // fused BN+ReLU on input
}

// Round 8
// 798.738 us; speedup vs baseline: 1.0326x; 1.0326x over previous
//
#include <hip/hip_runtime.h>

#define N_NODES 100000
#define N_EDGES 1600000
#define DIM 256
#define NBINS 196      // ceil(100000 / 512)
#define BINCAP 16384   // per-bin record capacity (expected 8163, sigma ~90)

typedef unsigned short bf16u;
typedef __attribute__((ext_vector_type(8))) short bf16x8s;
typedef __attribute__((ext_vector_type(4))) float f32x4;

__device__ __forceinline__ float bf2f(unsigned int u16) {
    union { unsigned int i; float f; } x; x.i = u16 << 16; return x.f;
}
__device__ __forceinline__ float hi2f(unsigned int u) {
    union { unsigned int i; float f; } x; x.i = u & 0xffff0000u; return x.f;
}
__device__ __forceinline__ float lo2f(unsigned int u) {
    union { unsigned int i; float f; } x; x.i = u << 16; return x.f;
}
__device__ __forceinline__ bf16u f2bf(float f) {
    union { float f; unsigned int i; } x; x.f = f;
    unsigned int i = x.i;
    return (bf16u)((i + 0x7fffu + ((i >> 16) & 1u)) >> 16);
}
__device__ __forceinline__ float loadv(const void* p, size_t i, int isf32) {
    return isf32 ? ((const float*)p)[i] : bf2f(((const bf16u*)p)[i]);
}
__device__ __forceinline__ void async_copy16(const void* g, void* l) {
    __builtin_amdgcn_global_load_lds((const __attribute__((address_space(1))) void*)g,
                                     (__attribute__((address_space(3))) void*)l, 16, 0, 0);
}

// ---------------- runtime format probes (+ zero bin fills + zero sums) ----------------
__global__ void detect_flags(const unsigned* xw, const int* ei, int* flags, int* gBinFill,
                             float* sums) {
    __shared__ int cnt, nz;
    if (threadIdx.x == 0) { cnt = 0; nz = 0; }
    __syncthreads();
    gBinFill[threadIdx.x] = 0;                     // 256 >= NBINS
#pragma unroll
    for (int i = 0; i < 6; ++i) sums[i * 256 + threadIdx.x] = 0.f;  // sums0..2, 1536 floats
    unsigned u = xw[threadIdx.x];
    float av = fabsf(bf2f(u & 0xffffu));
    if (av > 1e-5f && av < 50.f) atomicAdd(&cnt, 1);
    if (ei[2 * threadIdx.x + 1] != 0) atomicAdd(&nz, 1);
    __syncthreads();
    if (threadIdx.x == 0) {
        flags[0] = (cnt >= 128) ? 0 : 1;           // 1 = inputs are float32
        if (nz == 0) { flags[1] = 2; flags[2] = 2 * N_EDGES; }
        else         { flags[1] = 1; flags[2] = N_EDGES; }
    }
}

// ---------------- weight transpose: Wt[n][k] = bf16(W[k][n]) ----------------
__global__ void transpose_w(const void* W0, const void* W1, const void* W2, const void* W3,
                            bf16u* Wt, const int* flags) {
    __shared__ bf16u tile[64][65];
    int isf32 = flags[0];
    const void* W = (blockIdx.y == 0) ? W0 : (blockIdx.y == 1) ? W1 : (blockIdx.y == 2) ? W2 : W3;
    bf16u* out = Wt + (size_t)blockIdx.y * DIM * DIM;
    int t = threadIdx.x;
    int tx = t & 63, ty = t >> 6;
    int k0 = (blockIdx.x >> 2) * 64, n0 = (blockIdx.x & 3) * 64;
#pragma unroll
    for (int i = 0; i < 16; ++i) {
        int r = ty + i * 4;
        tile[tx][r] = f2bf(loadv(W, (size_t)(k0 + r) * DIM + (n0 + tx), isf32));
    }
    __syncthreads();
#pragma unroll
    for (int i = 0; i < 16; ++i) {
        int r = ty + i * 4;
        out[(size_t)(n0 + r) * DIM + (k0 + tx)] = tile[r][tx];
    }
}

// ---------------- CSR build, pass A: bucket scatter by dst>>9 ----------------
__global__ __launch_bounds__(256) void bin_scatter(const int* __restrict__ ei,
                                                   const int* __restrict__ flags,
                                                   uint2* __restrict__ gRec,
                                                   int* __restrict__ gBinFill) {
    __shared__ int cnt[256];       // bin counts, then bin bases
    __shared__ int cur[256];
    __shared__ uint2 rec[4096];    // 32 KB
    int t = threadIdx.x;
    cnt[t] = 0; cur[t] = 0;
    __syncthreads();
    int st = flags[1], ofs = flags[2];
    int e0 = blockIdx.x * 4096;
#pragma unroll
    for (int i = 0; i < 16; ++i) {
        int e = e0 + i * 256 + t;
        uint2 r;
        if (e < N_EDGES) {
            r.x = (unsigned)ei[(size_t)ofs + (size_t)e * st];
            r.y = (unsigned)ei[(size_t)e * st];
            atomicAdd(&cnt[r.x >> 9], 1);
        } else {
            r.x = 0xffffffffu; r.y = 0;
        }
        rec[i * 256 + t] = r;
    }
    __syncthreads();
    if (t < NBINS) {
        int c = cnt[t];
        int b = (c > 0) ? atomicAdd(&gBinFill[t], c) : 0;
        cnt[t] = b;                 // repurpose as base
    }
    __syncthreads();
#pragma unroll
    for (int i = 0; i < 16; ++i) {
        uint2 r = rec[i * 256 + t];
        if (r.x != 0xffffffffu) {
            int b = r.x >> 9;
            int li = atomicAdd(&cur[b], 1);
            int pos = cnt[b] + li;
            if (pos < BINCAP) gRec[(size_t)b * BINCAP + pos] = r;
        }
    }
}

// ---------------- CSR build, pass A2: exclusive scan over bin fills ----------------
__global__ void bin_scan(const int* gBinFill, int* binBase) {
    __shared__ int s[256];
    int t = threadIdx.x;
    s[t] = (t < NBINS) ? gBinFill[t] : 0;
    __syncthreads();
    for (int off = 1; off < 256; off <<= 1) {
        int v = (t >= off) ? s[t - off] : 0;
        __syncthreads();
        s[t] += v;
        __syncthreads();
    }
    binBase[t + 1] = s[t];
    if (t == 0) binBase[0] = 0;
}

// ---------------- CSR build, pass B: per-bin counting sort -> rp, col ----------------
__global__ __launch_bounds__(256) void bin_csr(const uint2* __restrict__ gRec,
                                               const int* __restrict__ gBinFill,
                                               const int* __restrict__ binBase,
                                               int* __restrict__ rp, int* __restrict__ col) {
    __shared__ int cntA[512], scanB[512], noff[512], ncur[512];
    int bin = blockIdx.x, t = threadIdx.x;
    int cnt = gBinFill[bin];
    if (cnt > BINCAP) cnt = BINCAP;
    int gbase = binBase[bin], lo = bin << 9;
    cntA[t] = 0; cntA[t + 256] = 0; ncur[t] = 0; ncur[t + 256] = 0;
    __syncthreads();
    const uint2* R = gRec + (size_t)bin * BINCAP;
    for (int j = t; j < cnt; j += 256) atomicAdd(&cntA[(int)R[j].x - lo], 1);
    __syncthreads();
    scanB[t] = cntA[t]; scanB[t + 256] = cntA[t + 256];
    __syncthreads();
    for (int off = 1; off < 512; off <<= 1) {
        int v0 = (t >= off) ? scanB[t - off] : 0;
        int v1 = (t + 256 >= off) ? scanB[t + 256 - off] : 0;
        __syncthreads();
        scanB[t] += v0; scanB[t + 256] += v1;
        __syncthreads();
    }
    noff[t] = scanB[t] - cntA[t];
    noff[t + 256] = scanB[t + 256] - cntA[t + 256];
    __syncthreads();
    int n0 = lo + t, n1 = lo + t + 256;
    if (n0 < N_NODES) rp[n0] = gbase + noff[t];
    if (n1 < N_NODES) rp[n1] = gbase + noff[t + 256];
    if (bin == 0 && t == 0) rp[N_NODES] = N_EDGES;
    for (int j = t; j < cnt; j += 256) {
        uint2 r = R[j];
        int k = (int)r.x - lo;
        int li = atomicAdd(&ncur[k], 1);
        col[gbase + noff[k] + li] = (int)r.y;
    }
}

// ---------------- BN0 column stats (dual dtype input) ----------------
__global__ void col_stats(const void* X, int nrows, float* sums, const int* flags, int dual) {
    __shared__ float ls[512];
    int isf32 = dual ? flags[0] : 0;
    int t = threadIdx.x;
    ls[t] = 0.f; ls[t + 256] = 0.f;
    __syncthreads();
    int rpb = (nrows + gridDim.x - 1) / gridDim.x;
    int r0 = blockIdx.x * rpb;
    int r1 = r0 + rpb; if (r1 > nrows) r1 = nrows;
    int cg = (t & 31) * 8;
    float s[8], q[8];
#pragma unroll
    for (int j = 0; j < 8; ++j) { s[j] = 0.f; q[j] = 0.f; }
    if (isf32) {
        for (int r = r0 + (t >> 5); r < r1; r += 8) {
            const float* xp = (const float*)X + (size_t)r * DIM + cg;
            f32x4 a = *(const f32x4*)xp, b = *(const f32x4*)(xp + 4);
#pragma unroll
            for (int j = 0; j < 4; ++j) {
                s[j] += a[j]; q[j] += a[j] * a[j];
                s[4 + j] += b[j]; q[4 + j] += b[j] * b[j];
            }
        }
    } else {
        for (int r = r0 + (t >> 5); r < r1; r += 8) {
            size_t base = (size_t)r * DIM + cg;
#pragma unroll
            for (int j = 0; j < 8; ++j) {
                float f = bf2f(((const bf16u*)X)[base + j]);
                s[j] += f; q[j] += f * f;
            }
        }
    }
#pragma unroll
    for (int j = 0; j < 8; ++j) {
        atomicAdd(&ls[cg + j], s[j]);
        atomicAdd(&ls[256 + cg + j], q[j]);
    }
    __syncthreads();
    atomicAdd(&sums[t], ls[t]);
    atomicAdd(&sums[256 + t], ls[256 + t]);
}

__global__ void bn_finalize(const float* sums, const void* gamma, const void* beta,
                            float* sc, float* sh, float inv_n, const int* flags) {
    int isf32 = flags[0];
    int t = threadIdx.x;
    float mu = sums[t] * inv_n;
    float var = sums[256 + t] * inv_n - mu * mu;
    float rs = rsqrtf(var + 1e-5f);
    float g = loadv(gamma, t, isf32), b = loadv(beta, t, isf32);
    sc[t] = rs * g;
    sh[t] = b - mu * rs * g;
}

// ---------------- vectorized BN apply (BN0 only): y = x*sc+sh, writes bf16 ----------------
__global__ void bn_apply(const void* X, const float* sc, const float* sh, bf16u* Y,
                         const int* flags, int dual, int relu) {
    int isf32 = dual ? flags[0] : 0;
    size_t i = (size_t)blockIdx.x * 256 + threadIdx.x;
    int c = ((int)(i & 31)) * 8;
    size_t base = i * 8;
    float v[8];
    if (isf32) {
        f32x4 x0 = *(const f32x4*)((const float*)X + base);
        f32x4 x1 = *(const f32x4*)((const float*)X + base + 4);
#pragma unroll
        for (int j = 0; j < 4; ++j) { v[j] = x0[j]; v[4 + j] = x1[j]; }
    } else {
        uint4 u = *(const uint4*)((const bf16u*)X + base);
        v[0] = lo2f(u.x); v[1] = hi2f(u.x);
        v[2] = lo2f(u.y); v[3] = hi2f(u.y);
        v[4] = lo2f(u.z); v[5] = hi2f(u.z);
        v[6] = lo2f(u.w); v[7] = hi2f(u.w);
    }
    f32x4 s0 = *(const f32x4*)(sc + c), s1 = *(const f32x4*)(sc + c + 4);
    f32x4 h0 = *(const f32x4*)(sh + c), h1 = *(const f32x4*)(sh + c + 4);
    float y[8];
#pragma unroll
    for (int j = 0; j < 4; ++j) {
        y[j]     = v[j]     * s0[j] + h0[j];
        y[4 + j] = v[4 + j] * s1[j] + h1[j];
    }
    if (relu) {
#pragma unroll
        for (int j = 0; j < 8; ++j) y[j] = fmaxf(y[j], 0.f);
    }
    uint4 ov;
    ov.x = (unsigned)f2bf(y[0]) | ((unsigned)f2bf(y[1]) << 16);
    ov.y = (unsigned)f2bf(y[2]) | ((unsigned)f2bf(y[3]) << 16);
    ov.z = (unsigned)f2bf(y[4]) | ((unsigned)f2bf(y[5]) << 16);
    ov.w = (unsigned)f2bf(y[6]) | ((unsigned)f2bf(y[7]) << 16);
    *(uint4*)(Y + base) = ov;
}

// ---------------- fused aggregate + GEMM + bias + stats ----------------
// Block: 64 output rows x full 256 cols. Phase 1: gather h[self]+sum(neighbors) into LDS
// (bf16, chunk-XOR swizzled). Phase 2: K-loop, A from LDS (no re-staging), B staged per kt.
__global__ __launch_bounds__(512) void agg_gemm(const bf16u* __restrict__ h,
                                                const int* __restrict__ rp,
                                                const int* __restrict__ col,
                                                const bf16u* __restrict__ Wt,
                                                const void* __restrict__ bias,
                                                bf16u* __restrict__ Cout,
                                                const int* __restrict__ flags,
                                                float* __restrict__ stats) {
    __shared__ __align__(16) bf16u aggA[64 * 256];  // 32 KB
    __shared__ __align__(16) bf16u Bs[256 * 64];    // 32 KB
    __shared__ float lsum[512];                     // [0..255] sums, [256..511] sumsq
    int isf32 = flags[0];
    int t = threadIdx.x;
    int w = t >> 6, lane = t & 63;
    lsum[t] = 0.f;
    int rb = blockIdx.x * 64;

    // ---- phase 1: gather 8 rows per wave into aggA ----
    {
        int p = lane >> 5, c = lane & 31;
        const uint4* hv = (const uint4*)h;          // 32 x 16B per row
        for (int i = 0; i < 8; ++i) {
            int lrow = w * 8 + i;
            int node = rb + lrow;
            if (node >= N_NODES) node = N_NODES - 1;   // pad rows: duplicate last (discarded)
            float acc[8];
            if (p == 0) {
                uint4 u = hv[(size_t)node * 32 + c];
                acc[0] = lo2f(u.x); acc[1] = hi2f(u.x);
                acc[2] = lo2f(u.y); acc[3] = hi2f(u.y);
                acc[4] = lo2f(u.z); acc[5] = hi2f(u.z);
                acc[6] = lo2f(u.w); acc[7] = hi2f(u.w);
            } else {
#pragma unroll
                for (int j = 0; j < 8; ++j) acc[j] = 0.f;
            }
            int e = rp[node], e1 = rp[node + 1];
            for (; e + 8 <= e1; e += 8) {
                int s0 = col[e + p], s1 = col[e + 2 + p], s2 = col[e + 4 + p], s3 = col[e + 6 + p];
                uint4 a = hv[(size_t)s0 * 32 + c];
                uint4 b = hv[(size_t)s1 * 32 + c];
                uint4 d = hv[(size_t)s2 * 32 + c];
                uint4 f = hv[(size_t)s3 * 32 + c];
                acc[0] += lo2f(a.x); acc[1] += hi2f(a.x); acc[2] += lo2f(a.y); acc[3] += hi2f(a.y);
                acc[4] += lo2f(a.z); acc[5] += hi2f(a.z); acc[6] += lo2f(a.w); acc[7] += hi2f(a.w);
                acc[0] += lo2f(b.x); acc[1] += hi2f(b.x); acc[2] += lo2f(b.y); acc[3] += hi2f(b.y);
                acc[4] += lo2f(b.z); acc[5] += hi2f(b.z); acc[6] += lo2f(b.w); acc[7] += hi2f(b.w);
                acc[0] += lo2f(d.x); acc[1] += hi2f(d.x); acc[2] += lo2f(d.y); acc[3] += hi2f(d.y);
                acc[4] += lo2f(d.z); acc[5] += hi2f(d.z); acc[6] += lo2f(d.w); acc[7] += hi2f(d.w);
                acc[0] += lo2f(f.x); acc[1] += hi2f(f.x); acc[2] += lo2f(f.y); acc[3] += hi2f(f.y);
                acc[4] += lo2f(f.z); acc[5] += hi2f(f.z); acc[6] += lo2f(f.w); acc[7] += hi2f(f.w);
            }
            for (; e + 4 <= e1; e += 4) {
                int s0 = col[e + p], s1 = col[e + 2 + p];
                uint4 a = hv[(size_t)s0 * 32 + c];
                uint4 b = hv[(size_t)s1 * 32 + c];
                acc[0] += lo2f(a.x); acc[1] += hi2f(a.x); acc[2] += lo2f(a.y); acc[3] += hi2f(a.y);
                acc[4] += lo2f(a.z); acc[5] += hi2f(a.z); acc[6] += lo2f(a.w); acc[7] += hi2f(a.w);
                acc[0] += lo2f(b.x); acc[1] += hi2f(b.x); acc[2] += lo2f(b.y); acc[3] += hi2f(b.y);
                acc[4] += lo2f(b.z); acc[5] += hi2f(b.z); acc[6] += lo2f(b.w); acc[7] += hi2f(b.w);
            }
            for (; e < e1; e += 2) {
                int idx = e + p;
                if (idx < e1) {
                    uint4 a = hv[(size_t)col[idx] * 32 + c];
                    acc[0] += lo2f(a.x); acc[1] += hi2f(a.x); acc[2] += lo2f(a.y); acc[3] += hi2f(a.y);
                    acc[4] += lo2f(a.z); acc[5] += hi2f(a.z); acc[6] += lo2f(a.w); acc[7] += hi2f(a.w);
                }
            }
#pragma unroll
            for (int j = 0; j < 8; ++j) acc[j] += __shfl_xor(acc[j], 32);
            if (p == 0) {
                uint4 ov;
                ov.x = (unsigned)f2bf(acc[0]) | ((unsigned)f2bf(acc[1]) << 16);
                ov.y = (unsigned)f2bf(acc[2]) | ((unsigned)f2bf(acc[3]) << 16);
                ov.z = (unsigned)f2bf(acc[4]) | ((unsigned)f2bf(acc[5]) << 16);
                ov.w = (unsigned)f2bf(acc[6]) | ((unsigned)f2bf(acc[7]) << 16);
                // chunk-XOR swizzle: LDS[row][chunk^(row&7)] = agg[row][chunk]
                *(uint4*)&aggA[lrow * 256 + ((c ^ (lrow & 7)) * 8)] = ov;
            }
        }
    }

    // ---- phase 2: K-loop; A from LDS, B staged per kt ----
    int lr = lane & 15, lq = lane >> 4;
    int wm = w >> 2, wn = w & 3;          // 2 x 4 wave grid over 64r x 256c
    f32x4 acc[2][4] = {};
    int srow = t >> 3;                    // 0..63
    int g8 = ((t & 7) ^ ((t >> 3) & 7)) * 8;
    for (int kt = 0; kt < 4; ++kt) {
        __syncthreads();                  // aggA ready (kt=0) / prior Bs reads done
#pragma unroll
        for (int p = 0; p < 4; ++p)
            async_copy16(Wt + (size_t)(p * 64 + srow) * 256 + kt * 64 + g8,
                         &Bs[(p * 64 + (w << 3)) * 64]);
        __syncthreads();                  // Bs landed (vmcnt drain at barrier)
#pragma unroll
        for (int ks = 0; ks < 2; ++ks) {
            bf16x8s af[2], bfv[4];
#pragma unroll
            for (int mt = 0; mt < 2; ++mt) {
                int ar = wm * 32 + mt * 16 + lr;
                int kc = kt * 8 + ks * 4 + lq;
                af[mt] = *(const bf16x8s*)&aggA[ar * 256 + ((kc ^ (lr & 7)) * 8)];
            }
#pragma unroll
            for (int nt = 0; nt < 4; ++nt) {
                int br = wn * 64 + nt * 16 + lr;
                bfv[nt] = *(const bf16x8s*)&Bs[br * 64 + (((ks * 4 + lq) ^ (lr & 7)) * 8)];
            }
#pragma unroll
            for (int mt = 0; mt < 2; ++mt)
#pragma unroll
                for (int nt = 0; nt < 4; ++nt)
                    acc[mt][nt] = __builtin_amdgcn_mfma_f32_16x16x32_bf16(af[mt], bfv[nt], acc[mt][nt], 0, 0, 0);
        }
    }

    // ---- epilogue: bias, bf16 store, fused column stats ----
#pragma unroll
    for (int nt = 0; nt < 4; ++nt) {
        int c = wn * 64 + nt * 16 + lr;
        float bv = loadv(bias, c, isf32);
        float ssum = 0.f, ssq = 0.f;
#pragma unroll
        for (int mt = 0; mt < 2; ++mt) {
            int r0 = rb + wm * 32 + mt * 16 + lq * 4;
#pragma unroll
            for (int j = 0; j < 4; ++j) {
                int r = r0 + j;
                if (r < N_NODES) {
                    float y = acc[mt][nt][j] + bv;
                    Cout[(size_t)r * 256 + c] = f2bf(y);
                    ssum += y; ssq += y * y;
                }
            }
        }
        atomicAdd(&lsum[c], ssum);
        atomicAdd(&lsum[256 + c], ssq);
    }
    __syncthreads();
    if (t < 256) {
        atomicAdd(&stats[t], lsum[t]);
        atomicAdd(&stats[256 + t], lsum[256 + t]);
    }
}

// ---------------- MFMA GEMM: double-buffered LDS, 1 barrier/K-iter, XCD-paired ----------------
// Used for the 2nd GEMM of each layer, with fused input-BN+ReLU (bnsc/bnsh).
__global__ __launch_bounds__(256) void gemm_bias(const bf16u* __restrict__ A,
                                                 const bf16u* __restrict__ Wt,
                                                 const void* __restrict__ bias,
                                                 void* __restrict__ Cout, int mrows,
                                                 const int* __restrict__ flags,
                                                 int relu, int f32out,
                                                 float* __restrict__ stats,
                                                 const float* __restrict__ bnsc,
                                                 const float* __restrict__ bnsh) {
    __shared__ bf16u As[2][128 * 64];   // 2 x 16 KB, XOR-swizzled k-chunks
    __shared__ bf16u Bs[2][128 * 64];
    __shared__ float lsum[256];
    int isf32 = flags[0];
    int t = threadIdx.x;
    int w = t >> 6, lane = t & 63;
    int lr = lane & 15, lq = lane >> 4;
    int wm = w >> 1, wn = w & 1;
    // bijective XCD chunk remap: nwg=1564, q=195, r=4 (m204)
    int xcd = blockIdx.x & 7, j0 = blockIdx.x >> 3;
    int wkid = ((xcd < 4) ? xcd * 196 : 784 + (xcd - 4) * 195) + j0;
    int rowBase = (wkid >> 1) * 128, colBase = (wkid & 1) * 128;
    f32x4 acc[4][4] = {};
    lsum[t] = 0.f;
    int srow = t >> 3;                           // 0..31
    int g8   = ((t & 7) ^ ((t >> 3) & 7)) * 8;   // swizzled k element offset
    int ldsOff = (t >> 3) * 64 + (t & 7) * 8;

    // ---- prologue: stage tile 0 ----
    if (bnsc) {
        f32x4 s0v = *(const f32x4*)(bnsc + g8);
        f32x4 s1v = *(const f32x4*)(bnsc + g8 + 4);
        f32x4 h0v = *(const f32x4*)(bnsh + g8);
        f32x4 h1v = *(const f32x4*)(bnsh + g8 + 4);
#pragma unroll
        for (int p = 0; p < 4; ++p) {
            int r = p * 32 + srow;
            int gr = rowBase + r; gr = (gr < mrows) ? gr : (mrows - 1);
            uint4 av = *(const uint4*)(A + (size_t)gr * 256 + g8);
            uint4 ov;
            ov.x = (unsigned)f2bf(fmaxf(lo2f(av.x) * s0v[0] + h0v[0], 0.f)) |
                   ((unsigned)f2bf(fmaxf(hi2f(av.x) * s0v[1] + h0v[1], 0.f)) << 16);
            ov.y = (unsigned)f2bf(fmaxf(lo2f(av.y) * s0v[2] + h0v[2], 0.f)) |
                   ((unsigned)f2bf(fmaxf(hi2f(av.y) * s0v[3] + h0v[3], 0.f)) << 16);
            ov.z = (unsigned)f2bf(fmaxf(lo2f(av.z) * s1v[0] + h1v[0], 0.f)) |
                   ((unsigned)f2bf(fmaxf(hi2f(av.z) * s1v[1] + h1v[1], 0.f)) << 16);
            ov.w = (unsigned)f2bf(fmaxf(lo2f(av.w) * s1v[2] + h1v[2], 0.f)) |
                   ((unsigned)f2bf(fmaxf(hi2f(av.w) * s1v[3] + h1v[3], 0.f)) << 16);
            *(uint4*)&As[0][p * 2048 + ldsOff] = ov;
            async_copy16(Wt + (size_t)(colBase + r) * 256 + g8, &Bs[0][(p * 32 + (w << 3)) * 64]);
        }
    } else {
#pragma unroll
        for (int p = 0; p < 4; ++p) {
            int r = p * 32 + srow;
            int gr = rowBase + r; gr = (gr < mrows) ? gr : (mrows - 1);
            async_copy16(A + (size_t)gr * 256 + g8, &As[0][(p * 32 + (w << 3)) * 64]);
            async_copy16(Wt + (size_t)(colBase + r) * 256 + g8, &Bs[0][(p * 32 + (w << 3)) * 64]);
        }
    }

    // ---- main loop: one barrier per K-iter ----
    for (int kt = 0; kt < 4; ++kt) {
        int b = kt & 1, bn = b ^ 1;
        int kn = (kt + 1) * 64;
        __syncthreads();                     // tile kt landed; prior reads drained
        uint4 av[4];
        if (kt < 3) {
            if (bnsc) {
#pragma unroll
                for (int p = 0; p < 4; ++p) {
                    int r = p * 32 + srow;
                    int gr = rowBase + r; gr = (gr < mrows) ? gr : (mrows - 1);
                    av[p] = *(const uint4*)(A + (size_t)gr * 256 + kn + g8);
                }
#pragma unroll
                for (int p = 0; p < 4; ++p) {
                    int r = p * 32 + srow;
                    async_copy16(Wt + (size_t)(colBase + r) * 256 + kn + g8,
                                 &Bs[bn][(p * 32 + (w << 3)) * 64]);
                }
            } else {
#pragma unroll
                for (int p = 0; p < 4; ++p) {
                    int r = p * 32 + srow;
                    int gr = rowBase + r; gr = (gr < mrows) ? gr : (mrows - 1);
                    async_copy16(A + (size_t)gr * 256 + kn + g8,
                                 &As[bn][(p * 32 + (w << 3)) * 64]);
                    async_copy16(Wt + (size_t)(colBase + r) * 256 + kn + g8,
                                 &Bs[bn][(p * 32 + (w << 3)) * 64]);
                }
            }
        }
#pragma unroll
        for (int ks = 0; ks < 2; ++ks) {
            bf16x8s af[4], bfv[4];
#pragma unroll
            for (int mt = 0; mt < 4; ++mt) {
                int ar = wm * 64 + mt * 16 + lr;
                af[mt] = *(const bf16x8s*)&As[b][ar * 64 + (((ks * 4 + lq) ^ (lr & 7)) * 8)];
            }
#pragma unroll
            for (int nt = 0; nt < 4; ++nt) {
                int br = wn * 64 + nt * 16 + lr;
                bfv[nt] = *(const bf16x8s*)&Bs[b][br * 64 + (((ks * 4 + lq) ^ (lr & 7)) * 8)];
            }
#pragma unroll
            for (int mt = 0; mt < 4; ++mt)
#pragma unroll
                for (int nt = 0; nt < 4; ++nt)
                    acc[mt][nt] = __builtin_amdgcn_mfma_f32_16x16x32_bf16(af[mt], bfv[nt], acc[mt][nt], 0, 0, 0);
        }
        if (bnsc && kt < 3) {
            f32x4 s0v = *(const f32x4*)(bnsc + kn + g8);
            f32x4 s1v = *(const f32x4*)(bnsc + kn + g8 + 4);
            f32x4 h0v = *(const f32x4*)(bnsh + kn + g8);
            f32x4 h1v = *(const f32x4*)(bnsh + kn + g8 + 4);
#pragma unroll
            for (int p = 0; p < 4; ++p) {
                uint4 ov;
                ov.x = (unsigned)f2bf(fmaxf(lo2f(av[p].x) * s0v[0] + h0v[0], 0.f)) |
                       ((unsigned)f2bf(fmaxf(hi2f(av[p].x) * s0v[1] + h0v[1], 0.f)) << 16);
                ov.y = (unsigned)f2bf(fmaxf(lo2f(av[p].y) * s0v[2] + h0v[2], 0.f)) |
                       ((unsigned)f2bf(fmaxf(hi2f(av[p].y) * s0v[3] + h0v[3], 0.f)) << 16);
                ov.z = (unsigned)f2bf(fmaxf(lo2f(av[p].z) * s1v[0] + h1v[0], 0.f)) |
                       ((unsigned)f2bf(fmaxf(hi2f(av[p].z) * s1v[1] + h1v[1], 0.f)) << 16);
                ov.w = (unsigned)f2bf(fmaxf(lo2f(av[p].w) * s1v[2] + h1v[2], 0.f)) |
                       ((unsigned)f2bf(fmaxf(hi2f(av[p].w) * s1v[3] + h1v[3], 0.f)) << 16);
                *(uint4*)&As[bn][p * 2048 + ldsOff] = ov;
            }
        }
    }

    int storef32 = f32out && isf32;
#pragma unroll
    for (int nt = 0; nt < 4; ++nt) {
        int cl = wn * 64 + nt * 16 + lr;
        int c = colBase + cl;
        float bv = loadv(bias, c, isf32);
#pragma unroll
        for (int mt = 0; mt < 4; ++mt) {
            int r0 = rowBase + wm * 64 + mt * 16 + lq * 4;
#pragma unroll
            for (int j = 0; j < 4; ++j) {
                int r = r0 + j;
                if (r < mrows) {
                    float y = acc[mt][nt][j] + bv;
                    if (relu) y = fmaxf(y, 0.f);
                    if (storef32) ((float*)Cout)[(size_t)r * 256 + c] = y;
                    else          ((bf16u*)Cout)[(size_t)r * 256 + c] = f2bf(y);
                }
            }
        }
    }
    (void)stats;
}

extern "C" void kernel_launch(void* const* d_in, const int* in_sizes, int n_in,
                              void* d_out, int out_size, void* d_ws, size_t ws_size,
                              hipStream_t stream) {
    const void* x   = d_in[0];
    const int*  ei  = (const int*)d_in[1];
    const void* g0  = d_in[2];
    const void* b0  = d_in[3];
    const void* W1a = d_in[4];
    const void* b1a = d_in[5];
    const void* g1  = d_in[6];
    const void* bt1 = d_in[7];
    const void* W1b = d_in[8];
    const void* b1b = d_in[9];
    const void* W2a = d_in[10];
    const void* b2a = d_in[11];
    const void* g2  = d_in[12];
    const void* bt2 = d_in[13];
    const void* W2b = d_in[14];
    const void* b2b = d_in[15];

    char* ws = (char*)d_ws;
    size_t off = 0;
    auto alloc = [&](size_t bytes) {
        char* p = ws + off;
        off += (bytes + 255) & ~(size_t)255;
        return p;
    };
    const size_t FB = (size_t)N_NODES * DIM * 2;
    bf16u* bufA  = (bf16u*)alloc(FB);
    bf16u* bufB  = (bf16u*)alloc(FB);
    bf16u* Wt    = (bf16u*)alloc((size_t)4 * DIM * DIM * 2);
    int*   colA  = (int*)alloc((size_t)N_EDGES * 4);
    int*   rp    = (int*)alloc((size_t)(N_NODES + 1) * 4);
    int*   gBinFill = (int*)alloc(256 * 4);
    int*   binBase  = (int*)alloc(260 * 4);
    float* sums0 = (float*)alloc(512 * 4);
    float* sums1 = (float*)alloc(512 * 4);
    float* sums2 = (float*)alloc(512 * 4);
    float* sc    = (float*)alloc(256 * 4);
    float* sh    = (float*)alloc(256 * 4);
    int*   flags = (int*)alloc(4 * 4);

    // bucket records reuse bufB (25.7 MB < 51.2 MB); bufB only becomes live at bn_apply
    uint2* gRec = (uint2*)bufB;

    bf16u* Wt1a = Wt;
    bf16u* Wt1b = Wt + 65536;
    bf16u* Wt2a = Wt + 2 * 65536;
    bf16u* Wt2b = Wt + 3 * 65536;

    const float inv_n = 1.0f / (float)N_NODES;

    detect_flags<<<1, 256, 0, stream>>>((const unsigned*)x, ei, flags, gBinFill, sums0);
    transpose_w<<<dim3(16, 4), 256, 0, stream>>>(W1a, W1b, W2a, W2b, Wt, flags);

    // CSR via 2-level bucket sort (writes coalesced; uses bufB as scratch)
    bin_scatter<<<391, 256, 0, stream>>>(ei, flags, gRec, gBinFill);
    bin_scan<<<1, 256, 0, stream>>>(gBinFill, binBase);
    bin_csr<<<NBINS, 256, 0, stream>>>(gRec, gBinFill, binBase, rp, colA);

    // BN0: x (f32) -> bufB (bf16)
    col_stats<<<500, 256, 0, stream>>>(x, N_NODES, sums0, flags, 1);
    bn_finalize<<<1, 256, 0, stream>>>(sums0, g0, b0, sc, sh, inv_n, flags);
    bn_apply<<<12500, 256, 0, stream>>>(x, sc, sh, bufB, flags, 1, 0);

    // layer 1: fused aggregate+GEMM, then BN+ReLU fused into 2nd GEMM
    agg_gemm<<<1563, 512, 0, stream>>>(bufB, rp, colA, Wt1a, b1a, bufA, flags, sums1);
    bn_finalize<<<1, 256, 0, stream>>>(sums1, g1, bt1, sc, sh, inv_n, flags);
    gemm_bias<<<1564, 256, 0, stream>>>(bufA, Wt1b, b1b, bufB, N_NODES, flags, 1, 0, nullptr,
                                        sc, sh);

    // layer 2
    agg_gemm<<<1563, 512, 0, stream>>>(bufB, rp, colA, Wt2a, b2a, bufA, flags, sums2);
    bn_finalize<<<1, 256, 0, stream>>>(sums2, g2, bt2, sc, sh, inv_n, flags);
    gemm_bias<<<1564, 256, 0, stream>>>(bufA, Wt2b, b2b, d_out, N_NODES, flags, 1, 1, nullptr,
                                        sc, sh);
}